// Round 8
// baseline (232.032 us; speedup 1.0000x reference)
//
#include <hip/hip_runtime.h>

// LSTM (B=8192, T=512, H=5) + MLP 5->32->32->5, fp32.
// Round 8: issue-bound redesign.
//  - Geometry: 8 lanes/row (lane j<5 owns unit j), 8 rows/wave, 1024 blocks
//    = exactly 1 wave/SIMD.
//  - h broadcast via DPP row-shifts (R3-PROVEN math: hc[t]=h_{j+t-4},
//    w9[G][t]=Whh[G*5+j][j+t-4], zero outside) -> cross-lane on the VALU
//    pipe (~8 cyc) instead of ds_bpermute (~120 cyc on the serial chain).
//  - x staged through LDS in 32-step double-buffered chunks. Padded row
//    stride 164 floats (656 B): the 8 groups' ds_read_b128 start at banks
//    4g (disjoint quads), and all 8 lanes of a group read the SAME address
//    (broadcast) -> conflict-free. Staging loads are issued a full chunk
//    (~6000 cyc) ahead -> HBM latency fully off the recurrence chain.
//    This also caps live registers (~150) so the allocator stops
//    spilling/sinking (R1/R6/R7 all collapsed to VGPR=76 with register
//    slabs: ~380 cyc/step of exposed load latency).
//  - Activation scales pre-folded into weights (R7-proven):
//    i,f,o: z*=-log2e, sig=rcp(1+exp2(z')); g: z*=2log2e, tanh=1-2rcp(1+exp2).

#define LOG2E 1.44269504088896f

__device__ __forceinline__ float hexp2(float x) { return __builtin_amdgcn_exp2f(x); }
__device__ __forceinline__ float hrcp(float x)  { return __builtin_amdgcn_rcpf(x); }

template<int CTRL>
__device__ __forceinline__ float dppf(float x) {
  int r = __builtin_amdgcn_update_dpp(0, __builtin_bit_cast(int, x),
                                      CTRL, 0xF, 0xF, true);
  return __builtin_bit_cast(float, r);
}

constexpr int TT   = 512;
constexpr int HD   = 5;
constexpr int RPB  = 8;     // rows per wave (8 lanes each)
constexpr int CHNK = 32;    // steps per LDS chunk
constexpr int RSTR = 164;   // padded LDS row stride in floats (656 B)
constexpr int XOFF = RPB * RSTR;           // 1312 floats per buffer
constexpr int NCH  = TT / CHNK;            // 16 chunks

__global__ __launch_bounds__(64, 1) void lstm_mlp_kernel(
    const float* __restrict__ x,   const float* __restrict__ Wih,
    const float* __restrict__ Whh, const float* __restrict__ bih,
    const float* __restrict__ bhh, const float* __restrict__ W1,
    const float* __restrict__ b1,  const float* __restrict__ W2,
    const float* __restrict__ b2,  const float* __restrict__ W3,
    const float* __restrict__ b3,  float* __restrict__ out, int B)
{
  const int lane = threadIdx.x;
  const int grp  = lane >> 3;           // row within block (0..7)
  const int j    = lane & 7;            // unit owned (valid if j<5)
  const int jj   = (j < 5) ? j : 0;
  const int blockRow = blockIdx.x * RPB;
  const int row  = blockRow + grp;
  const bool act = (j < 5) && (row < B);

  __shared__ float xbuf[2 * XOFF];      // 10.25 KB double buffer
  __shared__ float sh[RPB][5];
  __shared__ float s1[RPB][32];
  __shared__ float s2[RPB][32];

  // ---- per-lane weights, activation scale pre-folded ----
  float wih[4][5], w9[4][9], bsum[4];
#pragma unroll
  for (int G = 0; G < 4; ++G) {
    const float sc = (G == 2) ? (2.0f * LOG2E) : (-LOG2E);
#pragma unroll
    for (int k = 0; k < 5; ++k) wih[G][k] = Wih[(G * 5 + jj) * 5 + k] * sc;
    bsum[G] = (bih[G * 5 + jj] + bhh[G * 5 + jj]) * sc;
#pragma unroll
    for (int t = 0; t < 9; ++t) {
      int k = j + t - 4;                // hc[t] = h_{j+t-4}
      w9[G][t] = (j < 5 && k >= 0 && k < 5) ? Whh[(G * 5 + j) * 5 + k] * sc
                                            : 0.0f;
    }
  }

  // residual input x[row, 511, j] -- loaded once, off the chain
  const int rowc = (row < B) ? row : (B - 1);
  const float xlast = x[(size_t)rowc * (TT * HD) + 511 * HD + jj];

  // ---- staging setup: 5 units of 16B per lane per chunk ----
  // unit u = i*64+lane covers row r=u/40, 16B-offset o4=u%40 (in float4s)
  const float4* gp[5];
  int wa[5];
#pragma unroll
  for (int i = 0; i < 5; ++i) {
    int u  = i * 64 + lane;
    int r  = u / 40;
    int o4 = u - r * 40;
    int gr = blockRow + r; if (gr >= B) gr = B - 1;
    gp[i]  = (const float4*)(x + (size_t)gr * (TT * HD)) + o4;
    wa[i]  = r * RSTR + o4 * 4;
  }

  float4 st0, st1, st2, st3, st4;
  // chunk 0 -> stage -> buf0
  st0 = *gp[0]; gp[0] += 40; st1 = *gp[1]; gp[1] += 40;
  st2 = *gp[2]; gp[2] += 40; st3 = *gp[3]; gp[3] += 40;
  st4 = *gp[4]; gp[4] += 40;
  *(float4*)&xbuf[wa[0]] = st0; *(float4*)&xbuf[wa[1]] = st1;
  *(float4*)&xbuf[wa[2]] = st2; *(float4*)&xbuf[wa[3]] = st3;
  *(float4*)&xbuf[wa[4]] = st4;
  // chunk 1 -> stage
  st0 = *gp[0]; gp[0] += 40; st1 = *gp[1]; gp[1] += 40;
  st2 = *gp[2]; gp[2] += 40; st3 = *gp[3]; gp[3] += 40;
  st4 = *gp[4]; gp[4] += 40;

  // ---- recurrence state ----
  float c = 0.0f;
  float hc0 = 0.f, hc1 = 0.f, hc2 = 0.f, hc3 = 0.f, hc4 = 0.f,
        hc5 = 0.f, hc6 = 0.f, hc7 = 0.f, hc8 = 0.f;

  auto step = [&](float x0, float x1, float x2, float x3, float x4) {
    float z[4];
#pragma unroll
    for (int G = 0; G < 4; ++G) {
      float a0 = bsum[G];
      a0 = fmaf(x0, wih[G][0], a0);
      a0 = fmaf(x1, wih[G][1], a0);
      a0 = fmaf(x2, wih[G][2], a0);
      a0 = fmaf(x3, wih[G][3], a0);
      a0 = fmaf(x4, wih[G][4], a0);
      float p0 = 0.0f, p1 = 0.0f;     // two parallel h-chains
      p0 = fmaf(hc0, w9[G][0], p0);
      p0 = fmaf(hc1, w9[G][1], p0);
      p0 = fmaf(hc2, w9[G][2], p0);
      p0 = fmaf(hc3, w9[G][3], p0);
      p1 = fmaf(hc4, w9[G][4], p1);
      p1 = fmaf(hc5, w9[G][5], p1);
      p1 = fmaf(hc6, w9[G][6], p1);
      p1 = fmaf(hc7, w9[G][7], p1);
      p1 = fmaf(hc8, w9[G][8], p1);
      z[G] = a0 + p0 + p1;
    }
    float ig = hrcp(1.0f + hexp2(z[0]));
    float fg = hrcp(1.0f + hexp2(z[1]));
    float gv = fmaf(-2.0f, hrcp(1.0f + hexp2(z[2])), 1.0f);
    float og = hrcp(1.0f + hexp2(z[3]));
    c = fmaf(fg, c, ig * gv);
    float th = fmaf(-2.0f, hrcp(1.0f + hexp2(c * (2.0f * LOG2E))), 1.0f);
    float h  = og * th;
    hc0 = dppf<0x114>(h);   // row_shr:4 -> h_{j-4}
    hc1 = dppf<0x113>(h);   // h_{j-3}
    hc2 = dppf<0x112>(h);   // h_{j-2}
    hc3 = dppf<0x111>(h);   // h_{j-1}
    hc4 = h;
    hc5 = dppf<0x101>(h);   // row_shl:1 -> h_{j+1}
    hc6 = dppf<0x102>(h);   // h_{j+2}
    hc7 = dppf<0x103>(h);   // h_{j+3}
    hc8 = dppf<0x104>(h);   // h_{j+4}
  };

  auto step4 = [&](float4 A, float4 Bv, float4 C, float4 D, float4 E) {
    step(A.x, A.y, A.z, A.w, Bv.x);
    step(Bv.y, Bv.z, Bv.w, C.x, C.y);
    step(C.z, C.w, D.x, D.y, D.z);
    step(D.w, E.x, E.y, E.z, E.w);
  };

  auto rdg = [&](int fi, float4& A, float4& Bv, float4& C, float4& D, float4& E) {
    const float4* p = (const float4*)&xbuf[fi];
    A = p[0]; Bv = p[1]; C = p[2]; D = p[3]; E = p[4];
  };

  float4 A0, A1, A2, A3, A4;   // group buffer A (4 steps)
  float4 B0, B1, B2, B3, B4;   // group buffer B

#pragma unroll 1
  for (int ch = 0; ch < NCH; ++ch) {
    const int bo_cur  = (ch & 1) ? XOFF : 0;
    const int bo_next = XOFF - bo_cur;
    if (ch < NCH - 1) {   // stage chunk ch+1 into the other buffer
      *(float4*)&xbuf[wa[0] + bo_next] = st0;
      *(float4*)&xbuf[wa[1] + bo_next] = st1;
      *(float4*)&xbuf[wa[2] + bo_next] = st2;
      *(float4*)&xbuf[wa[3] + bo_next] = st3;
      *(float4*)&xbuf[wa[4] + bo_next] = st4;
    }
    if (ch < NCH - 2) {   // issue loads for chunk ch+2
      st0 = *gp[0]; gp[0] += 40; st1 = *gp[1]; gp[1] += 40;
      st2 = *gp[2]; gp[2] += 40; st3 = *gp[3]; gp[3] += 40;
      st4 = *gp[4]; gp[4] += 40;
    }
    const int xb = bo_cur + grp * RSTR;
    rdg(xb +   0, A0, A1, A2, A3, A4);
    rdg(xb +  20, B0, B1, B2, B3, B4);
    step4(A0, A1, A2, A3, A4); rdg(xb +  40, A0, A1, A2, A3, A4);
    step4(B0, B1, B2, B3, B4); rdg(xb +  60, B0, B1, B2, B3, B4);
    step4(A0, A1, A2, A3, A4); rdg(xb +  80, A0, A1, A2, A3, A4);
    step4(B0, B1, B2, B3, B4); rdg(xb + 100, B0, B1, B2, B3, B4);
    step4(A0, A1, A2, A3, A4); rdg(xb + 120, A0, A1, A2, A3, A4);
    step4(B0, B1, B2, B3, B4); rdg(xb + 140, B0, B1, B2, B3, B4);
    step4(A0, A1, A2, A3, A4);
    step4(B0, B1, B2, B3, B4);
  }

  // ---- MLP head (single wave; LDS writes then reads, wave-ordered) ----
  if (j < 5) sh[grp][j] = hc4 + xlast;    // h_j(T) + x[511,j]
  float in5_0 = sh[grp][0], in5_1 = sh[grp][1], in5_2 = sh[grp][2],
        in5_3 = sh[grp][3], in5_4 = sh[grp][4];

  // layer1: m = p*8 + j covers 0..31 over p=0..3
#pragma unroll
  for (int p = 0; p < 4; ++p) {
    int m = p * 8 + j;
    float acc = b1[m];
    acc = fmaf(W1[m * 5 + 0], in5_0, acc);
    acc = fmaf(W1[m * 5 + 1], in5_1, acc);
    acc = fmaf(W1[m * 5 + 2], in5_2, acc);
    acc = fmaf(W1[m * 5 + 3], in5_3, acc);
    acc = fmaf(W1[m * 5 + 4], in5_4, acc);
    s1[grp][m] = fmaxf(acc, 0.0f);
  }
  float y1[32];
#pragma unroll
  for (int k = 0; k < 32; ++k) y1[k] = s1[grp][k];

  auto dot32 = [&](const float* W, int m, const float* y, float b) {
    float acc = b;
    const float4* w4 = (const float4*)(W + m * 32);
#pragma unroll
    for (int k4 = 0; k4 < 8; ++k4) {
      float4 w = w4[k4];
      acc = fmaf(w.x, y[k4 * 4 + 0], acc);
      acc = fmaf(w.y, y[k4 * 4 + 1], acc);
      acc = fmaf(w.z, y[k4 * 4 + 2], acc);
      acc = fmaf(w.w, y[k4 * 4 + 3], acc);
    }
    return acc;
  };

#pragma unroll
  for (int p = 0; p < 4; ++p) {
    int m = p * 8 + j;
    s2[grp][m] = fmaxf(dot32(W2, m, y1, b2[m]), 0.0f);
  }
  float y2[32];
#pragma unroll
  for (int k = 0; k < 32; ++k) y2[k] = s2[grp][k];

  if (act) out[row * HD + j] = dot32(W3, j, y2, b3[j]);
}

extern "C" void kernel_launch(void* const* d_in, const int* in_sizes, int n_in,
                              void* d_out, int out_size, void* d_ws, size_t ws_size,
                              hipStream_t stream) {
  const float* x   = (const float*)d_in[0];
  const float* Wih = (const float*)d_in[1];
  const float* Whh = (const float*)d_in[2];
  const float* bih = (const float*)d_in[3];
  const float* bhh = (const float*)d_in[4];
  const float* W1  = (const float*)d_in[5];
  const float* b1  = (const float*)d_in[6];
  const float* W2  = (const float*)d_in[7];
  const float* b2  = (const float*)d_in[8];
  const float* W3  = (const float*)d_in[9];
  const float* b3  = (const float*)d_in[10];

  int B = in_sizes[0] / (TT * HD);
  int grid = (B + RPB - 1) / RPB;
  hipLaunchKernelGGL(lstm_mlp_kernel, dim3(grid), dim3(64), 0, stream,
                     x, Wih, Whh, bih, bhh, W1, b1, W2, b2, W3, b3,
                     (float*)d_out, B);
}

// Round 9
// 206.084 us; speedup vs baseline: 1.1259x; 1.1259x over previous
//
#include <hip/hip_runtime.h>

// LSTM (B=8192, T=512, H=5) + MLP 5->32->32->5, fp32.
// Round 9: issue-count diet on the R8 structure.
//  - R8 counters: VALUBusy 67% x 619 cyc/step = 413 issue cyc vs ~250
//    structural -> allocator was shuffling ~85 insts/step through AGPRs
//    (VGPR_Count stuck at 76). Fix: shrink register demand AND inst count.
//  - h broadcast: quad_perm(0x00/0x55/0xAA/0xFF) spreads h0..h3 in-quad;
//    5 bank-masked row_shr:4 / row_shl:4 merges (update_dpp with old)
//    complete the 8-lane-group broadcast. h-dot is now the TRUE 5-wide dot
//    (20 FMA/step, 20 weight regs) instead of the 9-wide padded one
//    (36 FMA, 36 regs).
//  - Single 10-FMA accumulator per gate (x-part first = off-chain; h-part
//    appended, 5 FMA from hv-ready): no combine adds.
//  - x staged through LDS (R8-proven): 32-step double-buffered chunks,
//    RSTR=164 floats -> 8 groups' ds_read_b128 hit disjoint bank quads,
//    8 lanes/group broadcast-read the same address. Conflict-free.
//  - Activation scales pre-folded (R7-proven).

#define LOG2E 1.44269504088896f

__device__ __forceinline__ float hexp2(float x) { return __builtin_amdgcn_exp2f(x); }
__device__ __forceinline__ float hrcp(float x)  { return __builtin_amdgcn_rcpf(x); }

// plain DPP move (all lanes written)
template<int CTRL>
__device__ __forceinline__ float dpp_mov(float x) {
  int r = __builtin_amdgcn_update_dpp(0, __builtin_bit_cast(int, x),
                                      CTRL, 0xF, 0xF, true);
  return __builtin_bit_cast(float, r);
}
// masked DPP merge: enabled banks get shifted src, others keep `old`
template<int CTRL, int BANKMASK>
__device__ __forceinline__ float dpp_merge(float old, float src) {
  int r = __builtin_amdgcn_update_dpp(__builtin_bit_cast(int, old),
                                      __builtin_bit_cast(int, src),
                                      CTRL, 0xF, BANKMASK, false);
  return __builtin_bit_cast(float, r);
}

constexpr int TT   = 512;
constexpr int HD   = 5;
constexpr int RPB  = 8;     // rows per wave (8 lanes each)
constexpr int CHNK = 32;    // steps per LDS chunk
constexpr int RSTR = 164;   // padded LDS row stride (656 B): group g at bank 4g
constexpr int XOFF = RPB * RSTR;
constexpr int NCH  = TT / CHNK;

__global__ __launch_bounds__(64, 1) void lstm_mlp_kernel(
    const float* __restrict__ x,   const float* __restrict__ Wih,
    const float* __restrict__ Whh, const float* __restrict__ bih,
    const float* __restrict__ bhh, const float* __restrict__ W1,
    const float* __restrict__ b1,  const float* __restrict__ W2,
    const float* __restrict__ b2,  const float* __restrict__ W3,
    const float* __restrict__ b3,  float* __restrict__ out, int B)
{
  const int lane = threadIdx.x;
  const int grp  = lane >> 3;           // row within block (0..7)
  const int j    = lane & 7;            // unit owned (valid if j<5)
  const int jj   = (j < 5) ? j : 0;
  const int blockRow = blockIdx.x * RPB;
  const int row  = blockRow + grp;
  const bool act = (j < 5) && (row < B);

  __shared__ float xbuf[2 * XOFF];
  __shared__ float sh[RPB][5];
  __shared__ float s1[RPB][32];
  __shared__ float s2[RPB][32];

  // ---- per-lane weights (rows {j,5+j,10+j,15+j}), activation pre-scaled --
  float wih[4][5], whh[4][5], bsum[4];
#pragma unroll
  for (int G = 0; G < 4; ++G) {
    const float sc = (G == 2) ? (2.0f * LOG2E) : (-LOG2E);
#pragma unroll
    for (int k = 0; k < 5; ++k) {
      wih[G][k] = Wih[(G * 5 + jj) * 5 + k] * sc;
      whh[G][k] = Whh[(G * 5 + jj) * 5 + k] * sc;
    }
    bsum[G] = (bih[G * 5 + jj] + bhh[G * 5 + jj]) * sc;
  }

  const int rowc = (row < B) ? row : (B - 1);
  const float xlast = x[(size_t)rowc * (TT * HD) + 511 * HD + jj];

  // ---- staging: 5x16B per lane per 32-step chunk ----
  const float4* gp[5];
  int wa[5];
#pragma unroll
  for (int i = 0; i < 5; ++i) {
    int u  = i * 64 + lane;
    int r  = u / 40;
    int o4 = u - r * 40;
    int gr = blockRow + r; if (gr >= B) gr = B - 1;
    gp[i]  = (const float4*)(x + (size_t)gr * (TT * HD)) + o4;
    wa[i]  = r * RSTR + o4 * 4;
  }

  float4 st0, st1, st2, st3, st4;
  st0 = *gp[0]; gp[0] += 40; st1 = *gp[1]; gp[1] += 40;
  st2 = *gp[2]; gp[2] += 40; st3 = *gp[3]; gp[3] += 40;
  st4 = *gp[4]; gp[4] += 40;
  *(float4*)&xbuf[wa[0]] = st0; *(float4*)&xbuf[wa[1]] = st1;
  *(float4*)&xbuf[wa[2]] = st2; *(float4*)&xbuf[wa[3]] = st3;
  *(float4*)&xbuf[wa[4]] = st4;
  st0 = *gp[0]; gp[0] += 40; st1 = *gp[1]; gp[1] += 40;
  st2 = *gp[2]; gp[2] += 40; st3 = *gp[3]; gp[3] += 40;
  st4 = *gp[4]; gp[4] += 40;

  // ---- recurrence state ----
  float c = 0.0f;
  float hv0 = 0.f, hv1 = 0.f, hv2 = 0.f, hv3 = 0.f, hv4 = 0.f;

  auto step = [&](float x0, float x1, float x2, float x3, float x4) {
    float z[4];
#pragma unroll
    for (int G = 0; G < 4; ++G) {
      float a = bsum[G];                 // x-part: independent of h
      a = fmaf(x0, wih[G][0], a);
      a = fmaf(x1, wih[G][1], a);
      a = fmaf(x2, wih[G][2], a);
      a = fmaf(x3, wih[G][3], a);
      a = fmaf(x4, wih[G][4], a);
      a = fmaf(hv0, whh[G][0], a);       // h-part: 5 FMA from hv-ready
      a = fmaf(hv1, whh[G][1], a);
      a = fmaf(hv2, whh[G][2], a);
      a = fmaf(hv3, whh[G][3], a);
      a = fmaf(hv4, whh[G][4], a);
      z[G] = a;
    }
    float ig = hrcp(1.0f + hexp2(z[0]));
    float fg = hrcp(1.0f + hexp2(z[1]));
    float gv = fmaf(-2.0f, hrcp(1.0f + hexp2(z[2])), 1.0f);
    float og = hrcp(1.0f + hexp2(z[3]));
    c = fmaf(fg, c, ig * gv);
    float th = fmaf(-2.0f, hrcp(1.0f + hexp2(c * (2.0f * LOG2E))), 1.0f);
    float h  = og * th;
    // ---- 5-value broadcast to the 8-lane group (all within 16-lane row) --
    // lanes j=0..4 hold h_0..h_4; quads: even quad = lanes j0..3 of a group,
    // odd quad = lanes j4..7 (lane j=4 holds h4).
    float q0 = dpp_mov<0x00>(h);         // quad lane0: even->h0, odd->h4
    float q1 = dpp_mov<0x55>(h);         // quad lane1: even->h1
    float q2 = dpp_mov<0xAA>(h);         // quad lane2: even->h2
    float q3 = dpp_mov<0xFF>(h);         // quad lane3: even->h3
    hv0 = dpp_merge<0x114, 0xA>(q0, q0); // row_shr:4 into odd banks
    hv1 = dpp_merge<0x114, 0xA>(q1, q1);
    hv2 = dpp_merge<0x114, 0xA>(q2, q2);
    hv3 = dpp_merge<0x114, 0xA>(q3, q3);
    hv4 = dpp_merge<0x104, 0x5>(q0, q0); // row_shl:4 into even banks
  };

  auto step4 = [&](float4 A, float4 Bv, float4 C, float4 D, float4 E) {
    step(A.x, A.y, A.z, A.w, Bv.x);
    step(Bv.y, Bv.z, Bv.w, C.x, C.y);
    step(C.z, C.w, D.x, D.y, D.z);
    step(D.w, E.x, E.y, E.z, E.w);
  };

  auto rdg = [&](int fi, float4& A, float4& Bv, float4& C, float4& D, float4& E) {
    const float4* p = (const float4*)&xbuf[fi];
    A = p[0]; Bv = p[1]; C = p[2]; D = p[3]; E = p[4];
  };

  float4 A0, A1, A2, A3, A4;
  float4 B0, B1, B2, B3, B4;

#pragma unroll 1
  for (int ch = 0; ch < NCH; ++ch) {
    const int bo_cur  = (ch & 1) ? XOFF : 0;
    const int bo_next = XOFF - bo_cur;
    if (ch < NCH - 1) {
      *(float4*)&xbuf[wa[0] + bo_next] = st0;
      *(float4*)&xbuf[wa[1] + bo_next] = st1;
      *(float4*)&xbuf[wa[2] + bo_next] = st2;
      *(float4*)&xbuf[wa[3] + bo_next] = st3;
      *(float4*)&xbuf[wa[4] + bo_next] = st4;
    }
    if (ch < NCH - 2) {
      st0 = *gp[0]; gp[0] += 40; st1 = *gp[1]; gp[1] += 40;
      st2 = *gp[2]; gp[2] += 40; st3 = *gp[3]; gp[3] += 40;
      st4 = *gp[4]; gp[4] += 40;
    }
    const int xb = bo_cur + grp * RSTR;
    rdg(xb +   0, A0, A1, A2, A3, A4);
    rdg(xb +  20, B0, B1, B2, B3, B4);
    step4(A0, A1, A2, A3, A4); rdg(xb +  40, A0, A1, A2, A3, A4);
    step4(B0, B1, B2, B3, B4); rdg(xb +  60, B0, B1, B2, B3, B4);
    step4(A0, A1, A2, A3, A4); rdg(xb +  80, A0, A1, A2, A3, A4);
    step4(B0, B1, B2, B3, B4); rdg(xb + 100, B0, B1, B2, B3, B4);
    step4(A0, A1, A2, A3, A4); rdg(xb + 120, A0, A1, A2, A3, A4);
    step4(B0, B1, B2, B3, B4); rdg(xb + 140, B0, B1, B2, B3, B4);
    step4(A0, A1, A2, A3, A4);
    step4(B0, B1, B2, B3, B4);
  }

  // ---- MLP head (single wave; no barriers needed) ----
  if (j < 5) sh[grp][j] = hv4 * 0.0f + (hv0 * 0.0f) + 0.0f +
                          ((j == 0) ? hv0 : (j == 1) ? hv1 : (j == 2) ? hv2 :
                           (j == 3) ? hv3 : hv4) + xlast;
  float in5_0 = sh[grp][0], in5_1 = sh[grp][1], in5_2 = sh[grp][2],
        in5_3 = sh[grp][3], in5_4 = sh[grp][4];

#pragma unroll
  for (int p = 0; p < 4; ++p) {
    int m = p * 8 + j;
    float acc = b1[m];
    acc = fmaf(W1[m * 5 + 0], in5_0, acc);
    acc = fmaf(W1[m * 5 + 1], in5_1, acc);
    acc = fmaf(W1[m * 5 + 2], in5_2, acc);
    acc = fmaf(W1[m * 5 + 3], in5_3, acc);
    acc = fmaf(W1[m * 5 + 4], in5_4, acc);
    s1[grp][m] = fmaxf(acc, 0.0f);
  }
  float y1[32];
#pragma unroll
  for (int k = 0; k < 32; ++k) y1[k] = s1[grp][k];

  auto dot32 = [&](const float* W, int m, const float* y, float b) {
    float acc = b;
    const float4* w4 = (const float4*)(W + m * 32);
#pragma unroll
    for (int k4 = 0; k4 < 8; ++k4) {
      float4 w = w4[k4];
      acc = fmaf(w.x, y[k4 * 4 + 0], acc);
      acc = fmaf(w.y, y[k4 * 4 + 1], acc);
      acc = fmaf(w.z, y[k4 * 4 + 2], acc);
      acc = fmaf(w.w, y[k4 * 4 + 3], acc);
    }
    return acc;
  };

#pragma unroll
  for (int p = 0; p < 4; ++p) {
    int m = p * 8 + j;
    s2[grp][m] = fmaxf(dot32(W2, m, y1, b2[m]), 0.0f);
  }
  float y2[32];
#pragma unroll
  for (int k = 0; k < 32; ++k) y2[k] = s2[grp][k];

  if (act) out[row * HD + j] = dot32(W3, j, y2, b3[j]);
}

extern "C" void kernel_launch(void* const* d_in, const int* in_sizes, int n_in,
                              void* d_out, int out_size, void* d_ws, size_t ws_size,
                              hipStream_t stream) {
  const float* x   = (const float*)d_in[0];
  const float* Wih = (const float*)d_in[1];
  const float* Whh = (const float*)d_in[2];
  const float* bih = (const float*)d_in[3];
  const float* bhh = (const float*)d_in[4];
  const float* W1  = (const float*)d_in[5];
  const float* b1  = (const float*)d_in[6];
  const float* W2  = (const float*)d_in[7];
  const float* b2  = (const float*)d_in[8];
  const float* W3  = (const float*)d_in[9];
  const float* b3  = (const float*)d_in[10];

  int B = in_sizes[0] / (TT * HD);
  int grid = (B + RPB - 1) / RPB;
  hipLaunchKernelGGL(lstm_mlp_kernel, dim3(grid), dim3(64), 0, stream,
                     x, Wih, Whh, bih, bhh, W1, b1, W2, b2, W3, b3,
                     (float*)d_out, B);
}